// Round 2
// baseline (1401.748 us; speedup 1.0000x reference)
//
#include <hip/hip_runtime.h>
#include <stdint.h>

typedef int   v4i  __attribute__((ext_vector_type(4)));
typedef int   v16i __attribute__((ext_vector_type(16)));
typedef float v4f  __attribute__((ext_vector_type(4)));

constexpr int M = 256, N = 28672, K = 8192;
constexpr int BN = 64, BK = 64;
constexpr int KITERS = K / BK;          // 128
constexpr int NB = N / BN;              // 448 n-tiles
constexpr int NTILES = NB * KITERS;     // 57344 (nb,it) fragment tiles
// q pre-tiled (unchanged): 128 kblocks x 16384 B, A-fragment order
//   addr(g, ks, lane) = g*2048 + ks*1024 + lane*16.
// Bp pre-tiled int8 weight, B-fragment order (byte-identical to the LDS image
// the previous kernel staged):  Bp[nb][it][ni][ks][lane][16]
//   value = weight[nb*64 + ni*32 + (lane&31)][it*64 + ks*32 + (lane>>5)*16 + b]

// ---------------------------------------------------------------------------
// Kernel 1: per-token int8 quant (x arrives as float32 per harness dtype rules)
// ---------------------------------------------------------------------------
__global__ __launch_bounds__(256) void quant_kernel(
    const float* __restrict__ x, int8_t* __restrict__ q,
    float* __restrict__ scales)
{
  const int m = blockIdx.x, t = threadIdx.x;
  const float* xr = x + (size_t)m * K;

  v4f v[8];
  float amax = 0.0f;
#pragma unroll
  for (int i = 0; i < 8; ++i) {
    v[i] = *(const v4f*)(xr + (i * 256 + t) * 4);  // coalesced float4
#pragma unroll
    for (int e = 0; e < 4; ++e) amax = fmaxf(amax, fabsf(v[i][e]));
  }
#pragma unroll
  for (int off = 32; off >= 1; off >>= 1)
    amax = fmaxf(amax, __shfl_xor(amax, off, 64));
  __shared__ float wmax[4];
  if ((t & 63) == 0) wmax[t >> 6] = amax;
  __syncthreads();
  amax = fmaxf(fmaxf(wmax[0], wmax[1]), fmaxf(wmax[2], wmax[3]));

  const float s = fmaxf(amax, 1e-5f) / 127.0f;  // IEEE div, matches ref
  if (t == 0) scales[m] = s;

  // element k = (i*256+t)*4 + e -> kblock = i*16 + (t>>4), s4 = (t>>2)&3
  const int s4 = (t >> 2) & 3;
  const size_t slotoff =
      (size_t)((m >> 5) * 128 + s4 * 32 + (m & 31)) * 16 + (t & 3) * 4;
#pragma unroll
  for (int i = 0; i < 8; ++i) {
    const int b0 = __float2int_rn(v[i][0] / s) & 255;
    const int b1 = __float2int_rn(v[i][1] / s) & 255;
    const int b2 = __float2int_rn(v[i][2] / s) & 255;
    const int b3 = __float2int_rn(v[i][3] / s);
    const int pk = b0 | (b1 << 8) | (b2 << 16) | (b3 << 24);
    const int kblock = i * 16 + (t >> 4);
    *(int*)(q + (size_t)kblock * 16384 + slotoff) = pk;
  }
}

// ---------------------------------------------------------------------------
// Kernel 2: weight prepack int32 -> int8 fragment tiles. Pure stream:
// 2048 blocks, no barriers, no LDS -> runs at HBM rate (~6 TB/s), unlike the
// latency-bound MFMA kernel that previously carried this 939 MB stream at
// ~1.7 TB/s. Each wave handles one (ni,ks) quarter-image: lane l reads 16
// consecutive int32 (one full 128B line shared with lane l+32), packs, and
// writes one dwordx4 -> wave store = 1 KB contiguous (perfectly coalesced).
// ---------------------------------------------------------------------------
__global__ __launch_bounds__(256) void prepack_kernel(
    const int* __restrict__ wgt, int8_t* __restrict__ bp)
{
  const int tid = threadIdx.x, lane = tid & 63, wv = tid >> 6;
  const int ni = wv >> 1, ks = wv & 1;
  for (int tile = blockIdx.x; tile < NTILES; tile += gridDim.x) {
    const int nb = tile >> 7;   // / KITERS
    const int it = tile & 127;  // % KITERS
    const int n  = nb * 64 + ni * 32 + (lane & 31);
    const int k0 = it * 64 + ks * 32 + (lane >> 5) * 16;
    const int* src = wgt + (size_t)n * K + k0;
    v4i o;
#pragma unroll
    for (int e = 0; e < 4; ++e) {
      const v4i w = *(const v4i*)(src + e * 4);
      o[e] = (w[0] & 255) | ((w[1] & 255) << 8) | ((w[2] & 255) << 16) |
             (w[3] << 24);
    }
    *(v4i*)(bp + ((size_t)tile * 4 + wv) * 1024 + lane * 16) = o;
  }
}

// ---------------------------------------------------------------------------
// Kernel 3: int8 GEMM, barrier-free / LDS-free. Both A and B fragments are
// direct coalesced dwordx4 global loads (A: 2 MB q, L2-resident; B: pre-tiled
// int8, 512 KB sequential stream per block, 4x less HBM than before, shared
// by the block's 4 M-waves via L1/L2). No __syncthreads in the K-loop ->
// no vmcnt drains, no lockstep; register ping-pong prefetch (static indexing,
// rule #20) lets the compiler issue next-iter loads under current MFMAs with
// counted vmcnt(8) waits.
// ---------------------------------------------------------------------------
__global__ __launch_bounds__(256, 2) void gemm_kernel(
    const int8_t* __restrict__ q, const int8_t* __restrict__ bp,
    const float* __restrict__ ascale, const float* __restrict__ cscale,
    const float* __restrict__ bias, float* __restrict__ out)
{
  __shared__ float ldsS[256];
  const int tid  = threadIdx.x;
  const int lane = tid & 63;
  const int wv   = tid >> 6;
  const int nb   = blockIdx.x;
  const int n0   = nb * BN;

  ldsS[tid] = ascale[tid];  // M == 256 == blockDim.x
  __syncthreads();          // once, outside the K-loop

  // wave wv owns M rows [64*wv, 64*wv+64); block owns N cols [n0, n0+64)
  const int8_t* abase = q + (size_t)wv * 4096 + lane * 16;
  const int8_t* bbase = bp + (size_t)nb * KITERS * 4096 + lane * 16;

  v4i aE[2][2], aO[2][2];  // [mi][ks]
  v4i bE[2][2], bO[2][2];  // [ni][ks]

  auto loadA = [&](int it, v4i (*a)[2]) {
#pragma unroll
    for (int mi = 0; mi < 2; ++mi)
#pragma unroll
      for (int ks = 0; ks < 2; ++ks)
        a[mi][ks] =
            *(const v4i*)(abase + (size_t)it * 16384 + mi * 2048 + ks * 1024);
  };
  auto loadB = [&](int it, v4i (*b)[2]) {
#pragma unroll
    for (int ni = 0; ni < 2; ++ni)
#pragma unroll
      for (int ks = 0; ks < 2; ++ks)
        b[ni][ks] =
            *(const v4i*)(bbase + (size_t)it * 4096 + ni * 2048 + ks * 1024);
  };

  v16i acc[2][2];
#pragma unroll
  for (int i = 0; i < 2; ++i)
#pragma unroll
    for (int j = 0; j < 2; ++j)
#pragma unroll
      for (int e = 0; e < 16; ++e) acc[i][j][e] = 0;

  // prologue
  loadA(0, aE);
  loadB(0, bE);

#define GSTEP(AC, BC, AN, BN_, IT)                                             \
  {                                                                            \
    if ((IT) + 1 < KITERS) { /* next-iter loads fly over current MFMAs */      \
      loadA((IT) + 1, AN);                                                     \
      loadB((IT) + 1, BN_);                                                    \
    }                                                                          \
    _Pragma("unroll")                                                          \
    for (int ks = 0; ks < 2; ++ks) {                                           \
      acc[0][0] = __builtin_amdgcn_mfma_i32_32x32x32_i8(AC[0][ks], BC[0][ks],  \
                                                        acc[0][0], 0, 0, 0);   \
      acc[0][1] = __builtin_amdgcn_mfma_i32_32x32x32_i8(AC[0][ks], BC[1][ks],  \
                                                        acc[0][1], 0, 0, 0);   \
      acc[1][0] = __builtin_amdgcn_mfma_i32_32x32x32_i8(AC[1][ks], BC[0][ks],  \
                                                        acc[1][0], 0, 0, 0);   \
      acc[1][1] = __builtin_amdgcn_mfma_i32_32x32x32_i8(AC[1][ks], BC[1][ks],  \
                                                        acc[1][1], 0, 0, 0);   \
    }                                                                          \
  }

  for (int it = 0; it < KITERS; it += 2) {
    GSTEP(aE, bE, aO, bO, it);
    GSTEP(aO, bO, aE, bE, it + 1);
  }
#undef GSTEP

  // epilogue: out[m,n] = acc * ascale[m] * cscale[n] + bias[n]
  // 32x32 C/D mapping (m74/m101): col = lane&31, row = (reg&3)+8*(reg>>2)+4*(lane>>5)
#pragma unroll
  for (int mi = 0; mi < 2; ++mi)
#pragma unroll
    for (int ni = 0; ni < 2; ++ni) {
      const int n_g = n0 + ni * 32 + (lane & 31);
      const float csn = cscale[n_g];
      const float bn  = bias[n_g];
      const int mbase = 64 * wv + mi * 32 + 4 * (lane >> 5);
#pragma unroll
      for (int reg = 0; reg < 16; ++reg) {
        const int mrow = mbase + (reg & 3) + 8 * (reg >> 2);
        out[(size_t)mrow * N + n_g] =
            (float)acc[mi][ni][reg] * ldsS[mrow] * csn + bn;
      }
    }
}

// ---------------------------------------------------------------------------
extern "C" void kernel_launch(void* const* d_in, const int* in_sizes, int n_in,
                              void* d_out, int out_size, void* d_ws, size_t ws_size,
                              hipStream_t stream) {
  const float* x      = (const float*)d_in[0];   // f16 in ref -> f32 on device
  const int*   wgt    = (const int*)d_in[1];     // int8 in ref -> int32 on device
  const float* cscale = (const float*)d_in[2];
  const float* bias   = (const float*)d_in[3];   // f16 in ref -> f32 on device
  float* out = (float*)d_out;

  int8_t* q      = (int8_t*)d_ws;                            // 2 MB, pre-tiled
  float*  ascale = (float*)((int8_t*)d_ws + (size_t)M * K);  // 256 f32
  int8_t* bp     = (int8_t*)d_ws + (4u << 20);               // 235 MB, pre-tiled

  quant_kernel<<<M, 256, 0, stream>>>(x, q, ascale);
  prepack_kernel<<<2048, 256, 0, stream>>>(wgt, bp);
  gemm_kernel<<<NB, 256, 0, stream>>>(q, bp, ascale, cscale, bias, out);
}